// Round 9
// baseline (518.292 us; speedup 1.0000x reference)
//
#include <hip/hip_runtime.h>

#define NB   16
#define NC   64
#define NPTS 65536
#define RES  32
#define R3   32768
#define PPB  2048   // points per block in reduction kernels (32 blocks/batch)

typedef float fx4 __attribute__((ext_vector_type(4)));   // clang-native for nontemporal builtins
typedef int   ix4 __attribute__((ext_vector_type(4)));

// ---------------- K1: partial sums for per-batch coord mean ----------------
__global__ void mean_partial(const float* __restrict__ coords, float* __restrict__ meanacc) {
    int bid = blockIdx.x;
    int b = bid >> 5, chunk = bid & 31;
    const float* cb = coords + (size_t)b * 3 * NPTS + chunk * PPB;
    float s0 = 0.f, s1 = 0.f, s2 = 0.f;
    for (int i = threadIdx.x; i < PPB; i += 256) {
        s0 += cb[i];
        s1 += cb[NPTS + i];
        s2 += cb[2 * NPTS + i];
    }
    for (int off = 32; off > 0; off >>= 1) {
        s0 += __shfl_down(s0, off);
        s1 += __shfl_down(s1, off);
        s2 += __shfl_down(s2, off);
    }
    if ((threadIdx.x & 63) == 0) {
        atomicAdd(&meanacc[b * 3 + 0], s0);
        atomicAdd(&meanacc[b * 3 + 1], s1);
        atomicAdd(&meanacc[b * 3 + 2], s2);
    }
}

// ---------------- K2: per-batch max L2 norm (atomicMax on int-reinterpreted float) ----------------
__global__ void maxnorm_partial(const float* __restrict__ coords,
                                const float* __restrict__ meanacc,
                                int* __restrict__ maxn) {
    int bid = blockIdx.x;
    int b = bid >> 5, chunk = bid & 31;
    const float* cb = coords + (size_t)b * 3 * NPTS + chunk * PPB;
    float m0 = meanacc[b * 3 + 0] * (1.0f / NPTS);
    float m1 = meanacc[b * 3 + 1] * (1.0f / NPTS);
    float m2 = meanacc[b * 3 + 2] * (1.0f / NPTS);
    float mx = 0.f;
    for (int i = threadIdx.x; i < PPB; i += 256) {
        float x = cb[i] - m0;
        float y = cb[NPTS + i] - m1;
        float z = cb[2 * NPTS + i] - m2;
        mx = fmaxf(mx, sqrtf(x * x + y * y + z * z));
    }
    for (int off = 32; off > 0; off >>= 1)
        mx = fmaxf(mx, __shfl_down(mx, off));
    if ((threadIdx.x & 63) == 0)
        atomicMax(&maxn[b], __float_as_int(mx));   // norms >= 0: int order == float order
}

// ---------------- K3: normalize coords (2nd output), voxel id, count histogram ----------------
__global__ void voxelize(const float* __restrict__ coords,
                         const float* __restrict__ meanacc,
                         const int* __restrict__ maxn,
                         float* __restrict__ ncout,
                         unsigned short* __restrict__ voxid,
                         unsigned int* __restrict__ cnt) {
    int t = blockIdx.x * 256 + threadIdx.x;
    int b = t >> 16, n = t & (NPTS - 1);
    const float* cb = coords + (size_t)b * 3 * NPTS;
    float m2 = __int_as_float(maxn[b]) * 2.0f;   // EPS = 0
    float c0 = meanacc[b * 3 + 0] * (1.0f / NPTS);
    float c1 = meanacc[b * 3 + 1] * (1.0f / NPTS);
    float c2 = meanacc[b * 3 + 2] * (1.0f / NPTS);
    float ncx = (cb[n]            - c0) / m2 + 0.5f;
    float ncy = (cb[NPTS + n]     - c1) / m2 + 0.5f;
    float ncz = (cb[2 * NPTS + n] - c2) / m2 + 0.5f;
    float sx = fminf(fmaxf(ncx * (float)RES, 0.f), (float)(RES - 1));
    float sy = fminf(fmaxf(ncy * (float)RES, 0.f), (float)(RES - 1));
    float sz = fminf(fmaxf(ncz * (float)RES, 0.f), (float)(RES - 1));
    float* nb = ncout + (size_t)b * 3 * NPTS;
    __builtin_nontemporal_store(sx, &nb[n]);             // pure streaming output
    __builtin_nontemporal_store(sy, &nb[NPTS + n]);
    __builtin_nontemporal_store(sz, &nb[2 * NPTS + n]);
    int v = (((int)rintf(sx)) << 10) + (((int)rintf(sy)) << 5) + (int)rintf(sz);
    voxid[t] = (unsigned short)v;
    atomicAdd(&cnt[((size_t)b << 15) + v], 1u);
}

// ---------------- K4: fused scatter-mean via per-(b,c) LDS grid slice ----------------
// One block per (batch, channel); the channel's 32x32x32 slice (32768 x 4B =
// 128 KB) lives in LDS. Fixed-point int accumulate -> native ds_add_u32
// (round-6 win). This round: DEPTH-2 explicit prefetch (two fx4+ushort4 in
// flight per thread - round-5/8 VGPR_Count=24 showed the compiler kept only
// one), and the count-divide folded into the epilogue (inv_cnt kernel and its
// 4 MB of traffic deleted). Nontemporal on the single-use feature stream and
// grid store; voxid/cnt stay cached (reused across the batch's 64 blocks).
__global__ __launch_bounds__(1024) void lds_grid(const float* __restrict__ features,
                                                 const unsigned short* __restrict__ voxid,
                                                 const unsigned int* __restrict__ cnt,
                                                 float* __restrict__ grid) {
    extern __shared__ int acc[];             // 32768 ints = 128 KB
    int b = blockIdx.x >> 6, c = blockIdx.x & 63;
    ix4* a4 = (ix4*)acc;
    for (int i = threadIdx.x; i < (R3 >> 2); i += 1024)
        a4[i] = (ix4){0, 0, 0, 0};
    __syncthreads();
    const fx4*     f4 = (const fx4*)(features + ((size_t)((b << 6) + c) << 16));
    const ushort4* v4 = (const ushort4*)(voxid + ((size_t)b << 16));
    fx4     f0 = __builtin_nontemporal_load(&f4[threadIdx.x]);
    fx4     f1 = __builtin_nontemporal_load(&f4[threadIdx.x + 1024]);
    ushort4 u0 = v4[threadIdx.x];
    ushort4 u1 = v4[threadIdx.x + 1024];
#pragma unroll
    for (int j = 0; j < 16; ++j) {           // 16384 fx4 rows / 1024 threads
        fx4     fn = f1;
        ushort4 vn = u1;
        if (j < 14) {
            fn = __builtin_nontemporal_load(&f4[threadIdx.x + ((j + 2) << 10)]);
            vn = v4[threadIdx.x + ((j + 2) << 10)];
        }
        atomicAdd(&acc[u0.x], (int)rintf(f0.x * 65536.0f));
        atomicAdd(&acc[u0.y], (int)rintf(f0.y * 65536.0f));
        atomicAdd(&acc[u0.z], (int)rintf(f0.z * 65536.0f));
        atomicAdd(&acc[u0.w], (int)rintf(f0.w * 65536.0f));
        f0 = f1; u0 = u1;
        f1 = fn; u1 = vn;
    }
    __syncthreads();
    const uint4* cb4 = (const uint4*)(cnt + ((size_t)b << 15));
    fx4* g4 = (fx4*)(grid + ((size_t)((b << 6) + c) << 15));
    for (int i = threadIdx.x; i < (R3 >> 2); i += 1024) {
        ix4   a = a4[i];
        uint4 k = cb4[i];
        fx4 o;
        o.x = (float)a.x * (1.0f / 65536.0f) / fmaxf((float)k.x, 1.0f);
        o.y = (float)a.y * (1.0f / 65536.0f) / fmaxf((float)k.y, 1.0f);
        o.z = (float)a.z * (1.0f / 65536.0f) / fmaxf((float)k.z, 1.0f);
        o.w = (float)a.w * (1.0f / 65536.0f) / fmaxf((float)k.w, 1.0f);
        __builtin_nontemporal_store(o, &g4[i]);
    }
}

extern "C" void kernel_launch(void* const* d_in, const int* in_sizes, int n_in,
                              void* d_out, int out_size, void* d_ws, size_t ws_size,
                              hipStream_t stream) {
    const float* features = (const float*)d_in[0];  // [16, 64, 65536]
    const float* coords   = (const float*)d_in[1];  // [16, 3, 65536]

    float* grid  = (float*)d_out;                    // [16, 64, 32768]
    float* ncout = grid + (size_t)NB * NC * R3;      // [16, 3, 65536]

    // ws: meanacc[48] | maxn[16] | pad->256B | cnt 2MB | voxid 2MB(u16)
    char* base = (char*)d_ws;
    float* meanacc = (float*)base;
    int*   maxn    = (int*)(base + 192);
    unsigned int*   cnt   = (unsigned int*)(base + 256);
    unsigned short* voxid = (unsigned short*)(cnt + (size_t)NB * R3);

    // zero meanacc/maxn/cnt (~2 MB)
    hipMemsetAsync(d_ws, 0, 256 + (size_t)NB * R3 * sizeof(unsigned int), stream);

    mean_partial   <<<NB * 32, 256, 0, stream>>>(coords, meanacc);
    maxnorm_partial<<<NB * 32, 256, 0, stream>>>(coords, meanacc, maxn);
    voxelize       <<<NB * NPTS / 256, 256, 0, stream>>>(coords, meanacc, maxn, ncout, voxid, cnt);
    lds_grid       <<<NB * NC, 1024, R3 * sizeof(int), stream>>>(features, voxid, cnt, grid);
}

// Round 10
// 516.512 us; speedup vs baseline: 1.0034x; 1.0034x over previous
//
#include <hip/hip_runtime.h>

#define NB   16
#define NC   64
#define NPTS 65536
#define RES  32
#define R3   32768
#define PPB  2048   // points per block in reduction kernels (32 blocks/batch)

typedef float fx4 __attribute__((ext_vector_type(4)));   // clang-native for nontemporal builtins
typedef int   ix4 __attribute__((ext_vector_type(4)));

// ---------------- K1: partial sums for per-batch coord mean ----------------
__global__ void mean_partial(const float* __restrict__ coords, float* __restrict__ meanacc) {
    int bid = blockIdx.x;
    int b = bid >> 5, chunk = bid & 31;
    const float* cb = coords + (size_t)b * 3 * NPTS + chunk * PPB;
    float s0 = 0.f, s1 = 0.f, s2 = 0.f;
    for (int i = threadIdx.x; i < PPB; i += 256) {
        s0 += cb[i];
        s1 += cb[NPTS + i];
        s2 += cb[2 * NPTS + i];
    }
    for (int off = 32; off > 0; off >>= 1) {
        s0 += __shfl_down(s0, off);
        s1 += __shfl_down(s1, off);
        s2 += __shfl_down(s2, off);
    }
    if ((threadIdx.x & 63) == 0) {
        atomicAdd(&meanacc[b * 3 + 0], s0);
        atomicAdd(&meanacc[b * 3 + 1], s1);
        atomicAdd(&meanacc[b * 3 + 2], s2);
    }
}

// ---------------- K2: per-batch max L2 norm (atomicMax on int-reinterpreted float) ----------------
__global__ void maxnorm_partial(const float* __restrict__ coords,
                                const float* __restrict__ meanacc,
                                int* __restrict__ maxn) {
    int bid = blockIdx.x;
    int b = bid >> 5, chunk = bid & 31;
    const float* cb = coords + (size_t)b * 3 * NPTS + chunk * PPB;
    float m0 = meanacc[b * 3 + 0] * (1.0f / NPTS);
    float m1 = meanacc[b * 3 + 1] * (1.0f / NPTS);
    float m2 = meanacc[b * 3 + 2] * (1.0f / NPTS);
    float mx = 0.f;
    for (int i = threadIdx.x; i < PPB; i += 256) {
        float x = cb[i] - m0;
        float y = cb[NPTS + i] - m1;
        float z = cb[2 * NPTS + i] - m2;
        mx = fmaxf(mx, sqrtf(x * x + y * y + z * z));
    }
    for (int off = 32; off > 0; off >>= 1)
        mx = fmaxf(mx, __shfl_down(mx, off));
    if ((threadIdx.x & 63) == 0)
        atomicMax(&maxn[b], __float_as_int(mx));   // norms >= 0: int order == float order
}

// ---------------- K3: normalize coords (2nd output), voxel id, count histogram ----------------
__global__ void voxelize(const float* __restrict__ coords,
                         const float* __restrict__ meanacc,
                         const int* __restrict__ maxn,
                         float* __restrict__ ncout,
                         unsigned short* __restrict__ voxid,
                         unsigned int* __restrict__ cnt) {
    int t = blockIdx.x * 256 + threadIdx.x;
    int b = t >> 16, n = t & (NPTS - 1);
    const float* cb = coords + (size_t)b * 3 * NPTS;
    float m2 = __int_as_float(maxn[b]) * 2.0f;   // EPS = 0
    float c0 = meanacc[b * 3 + 0] * (1.0f / NPTS);
    float c1 = meanacc[b * 3 + 1] * (1.0f / NPTS);
    float c2 = meanacc[b * 3 + 2] * (1.0f / NPTS);
    float ncx = (cb[n]            - c0) / m2 + 0.5f;
    float ncy = (cb[NPTS + n]     - c1) / m2 + 0.5f;
    float ncz = (cb[2 * NPTS + n] - c2) / m2 + 0.5f;
    float sx = fminf(fmaxf(ncx * (float)RES, 0.f), (float)(RES - 1));
    float sy = fminf(fmaxf(ncy * (float)RES, 0.f), (float)(RES - 1));
    float sz = fminf(fmaxf(ncz * (float)RES, 0.f), (float)(RES - 1));
    float* nb = ncout + (size_t)b * 3 * NPTS;
    __builtin_nontemporal_store(sx, &nb[n]);             // pure streaming output
    __builtin_nontemporal_store(sy, &nb[NPTS + n]);
    __builtin_nontemporal_store(sz, &nb[2 * NPTS + n]);
    int v = (((int)rintf(sx)) << 10) + (((int)rintf(sy)) << 5) + (int)rintf(sz);
    voxid[t] = (unsigned short)v;
    atomicAdd(&cnt[((size_t)b << 15) + v], 1u);
}

// ---------------- K4: persistent fused scatter-mean via per-CU LDS grid slice ----------------
// 256 blocks (1/CU). Block blk: xcd = blk&7, slot = blk>>3 -> batch b =
// 2*xcd + (slot>>4), channels cb_..cb_+3 (cb_ = (slot&15)*4). Each block
// processes its 4 channels sequentially over ONE batch:
//  - voxid loaded ONCE into registers (ushort4 us[16], statically indexed)
//    and reused across all 4 rounds (round 9 showed id reloads + addr VALU
//    in every round; now amortized 4x).
//  - feature prefetch bridges round boundaries: stream slots j=14,15 of
//    round p issue round p+1's first two loads, so HBM reads never drain
//    at the init/epilogue bubbles (the per-block-launch drain was the
//    round-9 structural residue).
//  - XCD-locality: all blocks of one XCD serve 2 batches -> their voxid/cnt
//    stay in that XCD's L2.
// Fixed-point int accumulate -> native ds_add_u32 (round-6 win). LDS slice
// single-buffered 128 KB; 3 barriers per round.
__global__ __launch_bounds__(1024) void lds_grid(const float* __restrict__ features,
                                                 const unsigned short* __restrict__ voxid,
                                                 const unsigned int* __restrict__ cnt,
                                                 float* __restrict__ grid) {
    extern __shared__ int acc[];             // 32768 ints = 128 KB
    int blk = blockIdx.x;                    // 256 blocks = 1/CU
    int xcd = blk & 7, slot = blk >> 3;
    int b   = (xcd << 1) + (slot >> 4);
    int cb_ = (slot & 15) << 2;              // 4 channels per block
    int tid = threadIdx.x;
    ix4* a4 = (ix4*)acc;

    // voxel ids for the whole batch, held in registers (16 x 8B = 32 VGPRs)
    const ushort4* v4 = (const ushort4*)(voxid + ((size_t)b << 16));
    ushort4 us[16];
#pragma unroll
    for (int j = 0; j < 16; ++j)
        us[j] = v4[tid + (j << 10)];

    const fx4* fbase = (const fx4*)(features + ((size_t)((b << 6) + cb_) << 16));
    const uint4* cb4 = (const uint4*)(cnt + ((size_t)b << 15));

    // prefetch round 0
    fx4 f0 = __builtin_nontemporal_load(&fbase[tid]);
    fx4 f1 = __builtin_nontemporal_load(&fbase[tid + 1024]);

    for (int p = 0; p < 4; ++p) {
        for (int i = tid; i < (R3 >> 2); i += 1024)
            a4[i] = (ix4){0, 0, 0, 0};
        __syncthreads();
        const fx4* f4  = fbase + ((size_t)p << 14);        // p * 65536/4
        const fx4* f4n = fbase + ((size_t)(p + 1) << 14);
#pragma unroll
        for (int j = 0; j < 16; ++j) {
            fx4 fn = f1;
            if (j < 14)
                fn = __builtin_nontemporal_load(&f4[tid + ((j + 2) << 10)]);
            else if (p < 3)                                // bridge into next round
                fn = __builtin_nontemporal_load(&f4n[tid + ((j - 14) << 10)]);
            ushort4 u = us[j];
            atomicAdd(&acc[u.x], (int)rintf(f0.x * 65536.0f));
            atomicAdd(&acc[u.y], (int)rintf(f0.y * 65536.0f));
            atomicAdd(&acc[u.z], (int)rintf(f0.z * 65536.0f));
            atomicAdd(&acc[u.w], (int)rintf(f0.w * 65536.0f));
            f0 = f1;
            f1 = fn;
        }
        __syncthreads();
        fx4* g4 = (fx4*)(grid + ((size_t)((b << 6) + cb_ + p) << 15));
        for (int i = tid; i < (R3 >> 2); i += 1024) {
            ix4   a = a4[i];
            uint4 k = cb4[i];
            fx4 o;
            o.x = (float)a.x * (1.0f / 65536.0f) / fmaxf((float)k.x, 1.0f);
            o.y = (float)a.y * (1.0f / 65536.0f) / fmaxf((float)k.y, 1.0f);
            o.z = (float)a.z * (1.0f / 65536.0f) / fmaxf((float)k.z, 1.0f);
            o.w = (float)a.w * (1.0f / 65536.0f) / fmaxf((float)k.w, 1.0f);
            __builtin_nontemporal_store(o, &g4[i]);
        }
        __syncthreads();                     // epilogue reads acc before next init writes
    }
}

extern "C" void kernel_launch(void* const* d_in, const int* in_sizes, int n_in,
                              void* d_out, int out_size, void* d_ws, size_t ws_size,
                              hipStream_t stream) {
    const float* features = (const float*)d_in[0];  // [16, 64, 65536]
    const float* coords   = (const float*)d_in[1];  // [16, 3, 65536]

    float* grid  = (float*)d_out;                    // [16, 64, 32768]
    float* ncout = grid + (size_t)NB * NC * R3;      // [16, 3, 65536]

    // ws: meanacc[48] | maxn[16] | pad->256B | cnt 2MB | voxid 2MB(u16)
    char* base = (char*)d_ws;
    float* meanacc = (float*)base;
    int*   maxn    = (int*)(base + 192);
    unsigned int*   cnt   = (unsigned int*)(base + 256);
    unsigned short* voxid = (unsigned short*)(cnt + (size_t)NB * R3);

    // zero meanacc/maxn/cnt (~2 MB)
    hipMemsetAsync(d_ws, 0, 256 + (size_t)NB * R3 * sizeof(unsigned int), stream);

    mean_partial   <<<NB * 32, 256, 0, stream>>>(coords, meanacc);
    maxnorm_partial<<<NB * 32, 256, 0, stream>>>(coords, meanacc, maxn);
    voxelize       <<<NB * NPTS / 256, 256, 0, stream>>>(coords, meanacc, maxn, ncout, voxid, cnt);
    lds_grid       <<<256, 1024, R3 * sizeof(int), stream>>>(features, voxid, cnt, grid);
}